// Round 4
// baseline (181.701 us; speedup 1.0000x reference)
//
#include <hip/hip_runtime.h>

// Until operator: r[t] = max( min(1,psi[t]), min(phi[t], r[t+1]) ), r[T] = -inf.
// f(x)=max(a,min(b,x)) closed under composition (f earlier in time):
//   (f o g): A = max(a_f, min(b_f, a_g)), B = min(b_f, b_g)
// float4 = 2 timesteps x 2 channels = one "pair entry". Row = 4096 entries.
// block = 8 waves; wave = contiguous 512-entry segment of each row.
//
// R8 structural change vs R4-R7: PIPELINE, not occupancy. Evidence: R7
// doubled occupancy (31->65%) at identical structure and gained nothing;
// R6 cut traffic and gained 8us. All pipes idle => co-phased load-burst /
// quiet / store-burst pattern is the limiter. Fix here:
//  (a) each block processes 2 ROWS as a 4-step pipeline (2 rows x 2
//      round-sequential 256-entry rounds through a 1024-float wave-private
//      LDS region); the loads of step s+1 issue right after step s's
//      G-build, so global loads stream CONTINUOUSLY through scan/carry/emit.
//  (b) the per-row ssum barrier is raw s_barrier + lgkmcnt(0) ONLY: vmcnt
//      is never drained (a __syncthreads would kill the in-flight prefetch).
//      ssum is dual-buffered by row to remove the WAR it used to cover.
//  (c) GA/GB of both rounds held in regs; peak live ~90 VGPR, under the
//      launch_bounds(512,4) cap of 128 (R5 lesson: verify cap >= live).
// LDS 32.3KB/block, grid 512 = exactly 2 resident blocks/CU, no tail.

#define T_LEN 8192
#define NSEG  8            // waves per block = segments per row
#define BLOCK (NSEG * 64)  // 512
#define RPB   2            // rows per block (pipeline depth)

__device__ __forceinline__ float rfl(float x) {
    return __int_as_float(__builtin_amdgcn_readfirstlane(__float_as_int(x)));
}

// Wave-level ordering fence for wave-private LDS reuse: prevents the compiler
// from moving LDS accesses across it; HW executes a wave's DS ops in order.
__device__ __forceinline__ void wave_lds_fence() {
    __asm__ volatile("" ::: "memory");
    __builtin_amdgcn_wave_barrier();
    __asm__ volatile("" ::: "memory");
}

// Block barrier that does NOT drain vmcnt: DS visibility only.
__device__ __forceinline__ void block_lds_barrier() {
    __asm__ volatile("s_waitcnt lgkmcnt(0)" ::: "memory");
    __builtin_amdgcn_s_barrier();
    __asm__ volatile("" ::: "memory");
}

__global__ __launch_bounds__(BLOCK, 4) void until_kernel(
    const float* __restrict__ phi_, const float* __restrict__ psi_,
    float* __restrict__ out_)
{
    const int  bid  = blockIdx.x;
    const int  tid  = threadIdx.x;
    const int  w    = tid >> 6;
    const int  lane = tid & 63;
    const float NEG = -__builtin_huge_valf();
    const float POS =  __builtin_huge_valf();

    const float4* __restrict__ phi4 = (const float4*)phi_;
    const float4* __restrict__ psi4 = (const float4*)psi_;
    float4* __restrict__ out4 = (float4*)out_;

    // float4-element base offset of this wave's 512-entry segment, per row
    const size_t rb[RPB] = {
        (size_t)(RPB * bid + 0) * (T_LEN / 2) + (size_t)w * 512,
        (size_t)(RPB * bid + 1) * (T_LEN / 2) + (size_t)w * 512
    };

    // Per-wave private 1024-float region, time-multiplexed per step:
    //   round G phase: 4 SoA comps x 256 entries (GAx/GAy/GBx/GBy)
    //   carry phase:   CX[e] at wl[e], CY[e] at wl[512+e]  (e in [0,512))
    __shared__ alignas(16) float lds[NSEG * 1024];
    __shared__ float4 ssum[RPB][NSEG];   // dual-buffered by row (no WAR)
    float* wl = lds + w * 1024;

    // ---- pipeline prologue: loads for step 0 = (row 0, round 0) ----
    float4 P[4], Q[4];
#pragma unroll
    for (int kl = 0; kl < 4; ++kl) {
        P[kl] = phi4[rb[0] + kl * 64 + lane];
        Q[kl] = psi4[rb[0] + kl * 64 + lane];
    }

#pragma unroll
    for (int row = 0; row < RPB; ++row) {
        float4 GAx[2], GAy[2], GBx[2], GBy[2];
        float  Sax[2], Say[2], Sbx[2], Sby[2];

#pragma unroll
        for (int r = 0; r < 2; ++r) {
            if (row + r) wave_lds_fence();  // WAR vs prior step's wl reads

            // ---- build pair functions G, SoA write (dense, conflict-free) ----
#pragma unroll
            for (int kl = 0; kl < 4; ++kl) {
                float* base = wl + kl * 64 + lane;
                float v0x = fminf(1.f, Q[kl].x), v0y = fminf(1.f, Q[kl].y);
                float v1x = fminf(1.f, Q[kl].z), v1y = fminf(1.f, Q[kl].w);
                base[0]   = fmaxf(v0x, fminf(P[kl].x, v1x));  // GAx
                base[256] = fmaxf(v0y, fminf(P[kl].y, v1y));  // GAy
                base[512] = fminf(P[kl].x, P[kl].z);          // GBx
                base[768] = fminf(P[kl].y, P[kl].w);          // GBy
            }

            // ---- prefetch for step s+1 (P,Q just died): continuous stream ----
            const int s = row * 2 + r;
            if (s < RPB * 2 - 1) {
                const size_t nb  = rb[(s + 1) >> 1];
                const int    nrd = (s + 1) & 1;
#pragma unroll
                for (int kl = 0; kl < 4; ++kl) {
                    P[kl] = phi4[nb + (nrd * 4 + kl) * 64 + lane];
                    Q[kl] = psi4[nb + (nrd * 4 + kl) * 64 + lane];
                }
            }
            wave_lds_fence();   // wave-private transpose: no block barrier

            // ---- transposed read (b128, dense) + compose + suffix scan ----
            GAx[r] = *(const float4*)(wl + 0 * 256 + lane * 4);
            GAy[r] = *(const float4*)(wl + 1 * 256 + lane * 4);
            GBx[r] = *(const float4*)(wl + 2 * 256 + lane * 4);
            GBy[r] = *(const float4*)(wl + 3 * 256 + lane * 4);

            // local compose right-to-left: H = G_j0 o G_j1 o G_j2 o G_j3
            float hax = GAx[r].w, hay = GAy[r].w, hbx = GBx[r].w, hby = GBy[r].w;
            hax = fmaxf(GAx[r].z, fminf(GBx[r].z, hax));
            hay = fmaxf(GAy[r].z, fminf(GBy[r].z, hay));
            hbx = fminf(GBx[r].z, hbx);
            hby = fminf(GBy[r].z, hby);
            hax = fmaxf(GAx[r].y, fminf(GBx[r].y, hax));
            hay = fmaxf(GAy[r].y, fminf(GBy[r].y, hay));
            hbx = fminf(GBx[r].y, hbx);
            hby = fminf(GBy[r].y, hby);
            hax = fmaxf(GAx[r].x, fminf(GBx[r].x, hax));
            hay = fmaxf(GAy[r].x, fminf(GBy[r].x, hay));
            hbx = fminf(GBx[r].x, hbx);
            hby = fminf(GBy[r].x, hby);

            // 64-lane inclusive SUFFIX scan (toward lane 63)
#pragma unroll
            for (int off = 1; off < 64; off <<= 1) {
                float gax = __shfl_down(hax, off), gay = __shfl_down(hay, off);
                float gbx = __shfl_down(hbx, off), gby = __shfl_down(hby, off);
                bool  val = (lane + off) < 64;
                gax = val ? gax : NEG;  gay = val ? gay : NEG;
                gbx = val ? gbx : POS;  gby = val ? gby : POS;
                hax = fmaxf(hax, fminf(hbx, gax));
                hay = fmaxf(hay, fminf(hby, gay));
                hbx = fminf(hbx, gbx);
                hby = fminf(hby, gby);
            }
            Sax[r] = hax; Say[r] = hay; Sbx[r] = hbx; Sby[r] = hby;
        }

        // ---- segment summary W = R0 o R1 -> ssum (non-draining barrier) ----
        float R0ax = rfl(Sax[0]), R0ay = rfl(Say[0]);
        float R0bx = rfl(Sbx[0]), R0by = rfl(Sby[0]);
        float R1ax = rfl(Sax[1]), R1ay = rfl(Say[1]);
        float R1bx = rfl(Sbx[1]), R1by = rfl(Sby[1]);
        if (lane == 0) {
            float wax = fmaxf(R0ax, fminf(R0bx, R1ax));
            float way = fmaxf(R0ay, fminf(R0by, R1ay));
            float wbx = fminf(R0bx, R1bx);
            float wby = fminf(R0by, R1by);
            ssum[row][w] = make_float4(wax, way, wbx, wby);
        }
        block_lds_barrier();   // lgkmcnt only: prefetch stays in flight
        float rcx = NEG, rcy = NEG;   // carry entering segment's right edge
        for (int j = NSEG - 1; j > w; --j) {
            float4 s4 = ssum[row][j];
            rcx = fmaxf(s4.x, fminf(s4.z, rcx));
            rcy = fmaxf(s4.y, fminf(s4.w, rcy));
        }

        // carries entering each round (round 0 sees round 1 applied first)
        float rinx[2], riny[2];
        rinx[1] = rcx;
        riny[1] = rcy;
        rinx[0] = fmaxf(R1ax, fminf(R1bx, rcx));
        riny[0] = fmaxf(R1ay, fminf(R1by, rcy));

        // ---- per-entry carries -> wave-private LDS (b128, dense) ----
        wave_lds_fence();   // WAR: round-1 transposed reads before overwrite
#pragma unroll
        for (int r = 0; r < 2; ++r) {
            // y = value at lane's LEFT edge = S_r[lane](r_in)
            float yx = fmaxf(Sax[r], fminf(Sbx[r], rinx[r]));
            float yy = fmaxf(Say[r], fminf(Sby[r], riny[r]));
            // carry entering lane's rightmost entry = y_{lane+1} (lane63: r_in)
            float cx = __shfl_down(yx, 1), cy = __shfl_down(yy, 1);
            if (lane == 63) { cx = rinx[r]; cy = riny[r]; }
            float4 CX, CY;
            CX.w = cx;
            CY.w = cy;
            CX.z = fmaxf(GAx[r].w, fminf(GBx[r].w, CX.w));
            CY.z = fmaxf(GAy[r].w, fminf(GBy[r].w, CY.w));
            CX.y = fmaxf(GAx[r].z, fminf(GBx[r].z, CX.z));
            CY.y = fmaxf(GAy[r].z, fminf(GBy[r].z, CY.z));
            CX.x = fmaxf(GAx[r].y, fminf(GBx[r].y, CX.y));
            CY.x = fmaxf(GAy[r].y, fminf(GBy[r].y, CY.y));
            *(float4*)(wl +       r * 256 + lane * 4) = CX;  // CX[e] at wl[e]
            *(float4*)(wl + 512 + r * 256 + lane * 4) = CY;  // CY[e] at wl[512+e]
        }
        wave_lds_fence();   // wave-private carry handoff: no block barrier

        // ---- emit: coalesced reload (L1/L2-warm) + carry from LDS ----
#pragma unroll
        for (int k = 0; k < 8; ++k) {
            const int e = k * 64 + lane;
            float4 P2 = phi4[rb[row] + e];
            float4 Q2 = psi4[rb[row] + e];
            float cx = wl[e];          // r at this entry's right edge
            float cy = wl[512 + e];
            float r1x = fmaxf(fminf(1.f, Q2.z), fminf(P2.z, cx));
            float r1y = fmaxf(fminf(1.f, Q2.w), fminf(P2.w, cy));
            float r0x = fmaxf(fminf(1.f, Q2.x), fminf(P2.x, r1x));
            float r0y = fmaxf(fminf(1.f, Q2.y), fminf(P2.y, r1y));
            out4[rb[row] + e] = make_float4(r0x, r0y, r1x, r1y);
        }
    }
}

extern "C" void kernel_launch(void* const* d_in, const int* in_sizes, int n_in,
                              void* d_out, int out_size, void* d_ws, size_t ws_size,
                              hipStream_t stream) {
    const float* phi = (const float*)d_in[0];
    const float* psi = (const float*)d_in[1];
    float* out = (float*)d_out;
    const int Bn = in_sizes[0] / (T_LEN * 2);  // = 1024 rows
    until_kernel<<<Bn / RPB, BLOCK, 0, stream>>>(phi, psi, out);
}

// Round 6
// 175.385 us; speedup vs baseline: 1.0360x; 1.0360x over previous
//
#include <hip/hip_runtime.h>

// Until operator: r[t] = max( min(1,psi[t]), min(phi[t], r[t+1]) ), r[T] = -inf.
// f(x)=max(a,min(b,x)) closed under composition (f earlier in time):
//   (f o g): A = max(a_f, min(b_f, a_g)), B = min(b_f, b_g)
// float4 = 2 timesteps x 2 channels = one "pair entry". Row = 4096 entries.
// block = one row (8 waves); wave = contiguous 512-entry segment.
//
// R9b = R6 + NON-TEMPORAL output stores (R9 retry: the builtin needs a
// native clang vector type, not HIP_vector_type -- ext_vector_type(4)
// alias fixes the compile error; layout is bit-identical to float4).
// Evidence chain R4-R8: every structural change at constant HBM traffic
// (occupancy 2x in R7, 2-row pipeline + non-draining barriers in R8)
// lands at 72-74us; only R6's traffic cut (FETCH 128->65.6MB) moved time
// (-8us). Kernel time tracks HBM bytes only => regime is L3-WORKING-SET-
// bound. R6's working set phi+psi+out = 192MB vs 256MB Infinity Cache:
// the 64MB/dispatch output stream (written, never read) evicts ~half the
// inputs each dispatch. nt stores give the output evict-early replacement,
// leaving the 128MB of inputs resident across dispatches -> HBM reads
// mostly vanish. Falsifiable: FETCH must drop below ~40MB, else theory
// wrong and ~66us is this access pattern's floor.
// (R6 notes kept: emit from REGISTERS, P/V held whole kernel, 64 VGPR,
//  launch_bounds(512,4); R5 lesson: never cap VGPR below peak live set.)

#define T_LEN 8192
#define NSEG  8            // waves per block = segments per row
#define BLOCK (NSEG * 64)  // 512

typedef float floatx4 __attribute__((ext_vector_type(4)));

__device__ __forceinline__ float rfl(float x) {
    return __int_as_float(__builtin_amdgcn_readfirstlane(__float_as_int(x)));
}

// Wave-level ordering fence for wave-private LDS reuse: prevents the compiler
// from moving LDS accesses across it; HW executes a wave's DS ops in order.
__device__ __forceinline__ void wave_lds_fence() {
    __asm__ volatile("" ::: "memory");
    __builtin_amdgcn_wave_barrier();
    __asm__ volatile("" ::: "memory");
}

// Non-temporal float4 store: stream/evict-early hint keeps the write-only
// output from polluting the Infinity Cache (inputs stay resident).
// Must go through a NATIVE vector type (ext_vector_type), not float4.
__device__ __forceinline__ void nt_store4(float4* p, float4 v) {
    floatx4 nv;
    nv.x = v.x; nv.y = v.y; nv.z = v.z; nv.w = v.w;
    __builtin_nontemporal_store(nv, (floatx4*)p);
}

__global__ __launch_bounds__(BLOCK, 4) void until_kernel(
    const float* __restrict__ phi, const float* __restrict__ psi,
    float* __restrict__ out)
{
    const int  row  = blockIdx.x;
    const int  tid  = threadIdx.x;
    const int  w    = tid >> 6;
    const int  lane = tid & 63;
    const float NEG = -__builtin_huge_valf();
    const float POS =  __builtin_huge_valf();

    const size_t segf4 = (size_t)row * (T_LEN / 2) + (size_t)w * 512;
    const float4* __restrict__ phi4 = (const float4*)phi + segf4;
    const float4* __restrict__ psi4 = (const float4*)psi + segf4;
    float4* __restrict__ out4 = (float4*)out + segf4;

    // Per-wave private 2048-float region:
    //   G phase:  round r in [r*1024, r*1024+1024): 4 SoA comps x 256 entries
    //   carry phase (reuses round-0 area): CX[e] at wl[e], CY[e] at wl[512+e]
    __shared__ alignas(16) float lds[NSEG * 2048];
    __shared__ float4 ssum[NSEG];
    float* wl = lds + w * 2048;

    // ---- burst: issue all 16 global loads back-to-back ----
    // P = phi raw; V = min(1, psi) folded at load (psi raw never needed again)
    float4 P[8], V[8];
#pragma unroll
    for (int k = 0; k < 8; ++k) {
        P[k] = phi4[k * 64 + lane];
        V[k] = psi4[k * 64 + lane];
    }
#pragma unroll
    for (int k = 0; k < 8; ++k) {
        V[k].x = fminf(1.f, V[k].x);
        V[k].y = fminf(1.f, V[k].y);
        V[k].z = fminf(1.f, V[k].z);
        V[k].w = fminf(1.f, V[k].w);
    }

    // ---- build pair functions G, SoA write (dense, conflict-free) ----
#pragma unroll
    for (int k = 0; k < 8; ++k) {
        const int r  = k >> 2;
        const int kl = k & 3;
        float* base = wl + r * 1024 + kl * 64 + lane;
        base[0]   = fmaxf(V[k].x, fminf(P[k].x, V[k].z));  // GAx
        base[256] = fmaxf(V[k].y, fminf(P[k].y, V[k].w));  // GAy
        base[512] = fminf(P[k].x, P[k].z);                 // GBx
        base[768] = fminf(P[k].y, P[k].w);                 // GBy
    }
    wave_lds_fence();   // wave-private transpose: no block barrier needed

    // ---- transposed read (b128, dense) + compose + suffix scan per round ----
    float4 GAx[2], GAy[2], GBx[2], GBy[2];
    float  Sax[2], Say[2], Sbx[2], Sby[2];
#pragma unroll
    for (int r = 0; r < 2; ++r) {
        const float* rb = wl + r * 1024;
        GAx[r] = *(const float4*)(rb + 0 * 256 + lane * 4);
        GAy[r] = *(const float4*)(rb + 1 * 256 + lane * 4);
        GBx[r] = *(const float4*)(rb + 2 * 256 + lane * 4);
        GBy[r] = *(const float4*)(rb + 3 * 256 + lane * 4);

        // local compose right-to-left: H = G_j0 o G_j1 o G_j2 o G_j3
        float hax = GAx[r].w, hay = GAy[r].w, hbx = GBx[r].w, hby = GBy[r].w;
        hax = fmaxf(GAx[r].z, fminf(GBx[r].z, hax));
        hay = fmaxf(GAy[r].z, fminf(GBy[r].z, hay));
        hbx = fminf(GBx[r].z, hbx);
        hby = fminf(GBy[r].z, hby);
        hax = fmaxf(GAx[r].y, fminf(GBx[r].y, hax));
        hay = fmaxf(GAy[r].y, fminf(GBy[r].y, hay));
        hbx = fminf(GBx[r].y, hbx);
        hby = fminf(GBy[r].y, hby);
        hax = fmaxf(GAx[r].x, fminf(GBx[r].x, hax));
        hay = fmaxf(GAy[r].x, fminf(GBy[r].x, hay));
        hbx = fminf(GBx[r].x, hbx);
        hby = fminf(GBy[r].x, hby);

        // 64-lane inclusive SUFFIX scan (toward lane 63)
#pragma unroll
        for (int off = 1; off < 64; off <<= 1) {
            float gax = __shfl_down(hax, off), gay = __shfl_down(hay, off);
            float gbx = __shfl_down(hbx, off), gby = __shfl_down(hby, off);
            bool  val = (lane + off) < 64;
            gax = val ? gax : NEG;  gay = val ? gay : NEG;
            gbx = val ? gbx : POS;  gby = val ? gby : POS;
            hax = fmaxf(hax, fminf(hbx, gax));
            hay = fmaxf(hay, fminf(hby, gay));
            hbx = fminf(hbx, gbx);
            hby = fminf(hby, gby);
        }
        Sax[r] = hax; Say[r] = hay; Sbx[r] = hbx; Sby[r] = hby;
    }

    // ---- segment summary W = R0 o R1 -> ssum (the ONE real barrier) ----
    float R0ax = rfl(Sax[0]), R0ay = rfl(Say[0]);
    float R0bx = rfl(Sbx[0]), R0by = rfl(Sby[0]);
    float R1ax = rfl(Sax[1]), R1ay = rfl(Say[1]);
    float R1bx = rfl(Sbx[1]), R1by = rfl(Sby[1]);
    if (lane == 0) {
        float wax = fmaxf(R0ax, fminf(R0bx, R1ax));
        float way = fmaxf(R0ay, fminf(R0by, R1ay));
        float wbx = fminf(R0bx, R1bx);
        float wby = fminf(R0by, R1by);
        ssum[w] = make_float4(wax, way, wbx, wby);
    }
    __syncthreads();
    float rcx = NEG, rcy = NEG;   // carry entering this segment's right edge
    for (int j = NSEG - 1; j > w; --j) {
        float4 s = ssum[j];
        rcx = fmaxf(s.x, fminf(s.z, rcx));
        rcy = fmaxf(s.y, fminf(s.w, rcy));
    }

    // carries entering each round (round 0 sees round 1 applied first)
    float rinx[2], riny[2];
    rinx[1] = rcx;
    riny[1] = rcy;
    rinx[0] = fmaxf(R1ax, fminf(R1bx, rcx));
    riny[0] = fmaxf(R1ay, fminf(R1by, rcy));

    // ---- per-entry carries -> wave-private LDS (b128, dense) ----
#pragma unroll
    for (int r = 0; r < 2; ++r) {
        // y = value at lane's LEFT edge = S_r[lane](r_in)
        float yx = fmaxf(Sax[r], fminf(Sbx[r], rinx[r]));
        float yy = fmaxf(Say[r], fminf(Sby[r], riny[r]));
        // carry entering lane's rightmost entry = y_{lane+1} (lane63: r_in)
        float cx = __shfl_down(yx, 1), cy = __shfl_down(yy, 1);
        if (lane == 63) { cx = rinx[r]; cy = riny[r]; }
        float4 CX, CY;
        CX.w = cx;
        CY.w = cy;
        CX.z = fmaxf(GAx[r].w, fminf(GBx[r].w, CX.w));
        CY.z = fmaxf(GAy[r].w, fminf(GBy[r].w, CY.w));
        CX.y = fmaxf(GAx[r].z, fminf(GBx[r].z, CX.z));
        CY.y = fmaxf(GAy[r].z, fminf(GBy[r].z, CY.z));
        CX.x = fmaxf(GAx[r].y, fminf(GBx[r].y, CX.y));
        CY.x = fmaxf(GAy[r].y, fminf(GBy[r].y, CY.y));
        *(float4*)(wl +       r * 256 + lane * 4) = CX;  // CX[e] at wl[e]
        *(float4*)(wl + 512 + r * 256 + lane * 4) = CY;  // CY[e] at wl[512+e]
    }
    wave_lds_fence();   // wave-private carry handoff: no block barrier

    // ---- emit outputs from REGISTERS + carry from LDS; nt stores ----
#pragma unroll
    for (int k = 0; k < 8; ++k) {
        const int e = k * 64 + lane;
        float cx = wl[e];          // r at this entry's right edge
        float cy = wl[512 + e];
        float r1x = fmaxf(V[k].z, fminf(P[k].z, cx));
        float r1y = fmaxf(V[k].w, fminf(P[k].w, cy));
        float r0x = fmaxf(V[k].x, fminf(P[k].x, r1x));
        float r0y = fmaxf(V[k].y, fminf(P[k].y, r1y));
        nt_store4(&out4[e], make_float4(r0x, r0y, r1x, r1y));
    }
}

extern "C" void kernel_launch(void* const* d_in, const int* in_sizes, int n_in,
                              void* d_out, int out_size, void* d_ws, size_t ws_size,
                              hipStream_t stream) {
    const float* phi = (const float*)d_in[0];
    const float* psi = (const float*)d_in[1];
    float* out = (float*)d_out;
    const int Bn = in_sizes[0] / (T_LEN * 2);  // = 1024
    until_kernel<<<Bn, BLOCK, 0, stream>>>(phi, psi, out);
}